// Round 4
// baseline (639.316 us; speedup 1.0000x reference)
//
#include <hip/hip_runtime.h>
#include <hip/hip_bf16.h>

// Relative-position causal attention, B=4 H=16 Q=K=1024 D=64 (fp32 in/out).
// d_out = [output (BH*Q*D) | p_attn (BH*Q*K)] fp32.
// K1 content scores -> K2a rel + exp (reg-double-buffered prefetch, unnormalized,
// partial sums to ws) -> K3 P@V (scales by 1/sum, normalizes P in place) ->
// K4 P@bigr_v (LDS double-buffered, 1 sync/step, reg prefetch).

#define BH 64
#define SQ 1024
#define SK 1024
#define DH 64
#define SCALE 0.125f

typedef __attribute__((ext_vector_type(4))) float f32x4;
typedef __attribute__((ext_vector_type(8))) unsigned short ushort8;
typedef __attribute__((ext_vector_type(8))) __bf16 bf16x8;

static __device__ inline unsigned short f2bf(float x) {
    unsigned u = __float_as_uint(x);
    unsigned r = u + 0x7FFFu + ((u >> 16) & 1u);
    return (unsigned short)(r >> 16);
}
static __device__ inline float bf2f(unsigned short s) {
    return __uint_as_float(((unsigned)s) << 16);
}

struct Frag2 { bf16x8 h, l; };

static __device__ inline Frag2 load_split(const float* __restrict__ p) {
    float4 x0 = *reinterpret_cast<const float4*>(p);
    float4 x1 = *reinterpret_cast<const float4*>(p + 4);
    float v[8] = {x0.x, x0.y, x0.z, x0.w, x1.x, x1.y, x1.z, x1.w};
    ushort8 uh, ul;
#pragma unroll
    for (int j = 0; j < 8; ++j) {
        unsigned short h = f2bf(v[j]);
        float r = v[j] - bf2f(h);
        uh[j] = h;
        ul[j] = f2bf(r);
    }
    Frag2 f;
    f.h = __builtin_bit_cast(bf16x8, uh);
    f.l = __builtin_bit_cast(bf16x8, ul);
    return f;
}

static __device__ inline bf16x8 pack_bf8(float4 x0, float4 x1) {
    float v[8] = {x0.x, x0.y, x0.z, x0.w, x1.x, x1.y, x1.z, x1.w};
    ushort8 u;
#pragma unroll
    for (int j = 0; j < 8; ++j) u[j] = f2bf(v[j]);
    return __builtin_bit_cast(bf16x8, u);
}

static __device__ inline bf16x8 load_bf8(const float* __restrict__ p) {
    float4 x0 = *reinterpret_cast<const float4*>(p);
    float4 x1 = *reinterpret_cast<const float4*>(p + 4);
    return pack_bf8(x0, x1);
}

static __device__ inline bf16x8 load_bf8_strided(const float* __restrict__ p, int stride) {
    ushort8 u;
#pragma unroll
    for (int j = 0; j < 8; ++j) u[j] = f2bf(p[(size_t)j * stride]);
    return __builtin_bit_cast(bf16x8, u);
}

#define MFMA(a, b, c) __builtin_amdgcn_mfma_f32_16x16x32_bf16((a), (b), (c), 0, 0, 0)

static __device__ inline f32x4 mfma_split(const Frag2& a, const Frag2& b, f32x4 c) {
    c = MFMA(a.h, b.h, c);
    c = MFMA(a.h, b.l, c);
    c = MFMA(a.l, b.h, c);
    return c;
}

// ---------------- K1: content scores Q@K^T * scale -> P region (zeros above diag)
__global__ __launch_bounds__(256) void k_scores(const float* __restrict__ q,
                                                const float* __restrict__ k,
                                                float* __restrict__ P) {
    const int kt = blockIdx.x, qt = blockIdx.y, bh = blockIdx.z;
    const int tid = threadIdx.x;
    const int kbase = kt * 64;
    if (kbase > qt * 64 + 63) {  // fully masked tile: zeros
        const int row = qt * 64 + (tid >> 2);
        float4 z = {0.f, 0.f, 0.f, 0.f};
        float4* dst = reinterpret_cast<float4*>(
            &P[((size_t)bh * SQ + row) * SK + kbase + (tid & 3) * 16]);
        dst[0] = z; dst[1] = z; dst[2] = z; dst[3] = z;
        return;
    }
    const int w = tid >> 6, l = tid & 63;
    const int lm = l & 15, lg = l >> 4;
    const int q0 = qt * 64 + w * 16;
    const float* qrow = q + ((size_t)bh * SQ + q0 + lm) * DH + lg * 8;
    Frag2 a0 = load_split(qrow);
    Frag2 a1 = load_split(qrow + 32);
#pragma unroll
    for (int nt = 0; nt < 4; ++nt) {
        const int kc = kbase + nt * 16 + lm;
        f32x4 acc = {0.f, 0.f, 0.f, 0.f};
        if (kbase + nt * 16 <= q0 + 15) {
            const float* krow = k + ((size_t)bh * SK + kc) * DH + lg * 8;
            Frag2 b0 = load_split(krow);
            Frag2 b1 = load_split(krow + 32);
            acc = mfma_split(a0, b0, acc);
            acc = mfma_split(a1, b1, acc);
        }
#pragma unroll
        for (int r = 0; r < 4; ++r) {
            const int qq = q0 + lg * 4 + r;
            float v = (kc <= qq) ? acc[r] * SCALE : 0.f;
            P[((size_t)bh * SQ + qq) * SK + kc] = v;
        }
    }
}

// ---------------- K2a helpers: 32-k-row step, register double-buffered ----------
// A (bigr_k) single bf16, B (query) split bf16: 4 MFMA per 16-row subtile.
struct StepBuf { float4 a[8]; float4 p[2]; };

static __device__ inline void k2_issue(int k0, const float* __restrict__ bk,
                                       const float* __restrict__ prow,
                                       int lm, int lg, StepBuf& B) {
#pragma unroll
    for (int nt = 0; nt < 2; ++nt) {
        const float* arow = bk + (size_t)(k0 + nt * 16 + lm) * DH + lg * 8;
        B.a[nt * 4 + 0] = *reinterpret_cast<const float4*>(arow);
        B.a[nt * 4 + 1] = *reinterpret_cast<const float4*>(arow + 4);
        B.a[nt * 4 + 2] = *reinterpret_cast<const float4*>(arow + 32);
        B.a[nt * 4 + 3] = *reinterpret_cast<const float4*>(arow + 36);
        B.p[nt] = *reinterpret_cast<const float4*>(prow + k0 + nt * 16 + lg * 4);
    }
}

static __device__ inline void k2_compute(int k0, const StepBuf& B,
                                         const Frag2& qb0, const Frag2& qb1,
                                         int lg, int KE, float* __restrict__ prow,
                                         float& lsum) {
#pragma unroll
    for (int nt = 0; nt < 2; ++nt) {
        bf16x8 alo = pack_bf8(B.a[nt * 4 + 0], B.a[nt * 4 + 1]);
        bf16x8 ahi = pack_bf8(B.a[nt * 4 + 2], B.a[nt * 4 + 3]);
        f32x4 acc = {0.f, 0.f, 0.f, 0.f};
        acc = MFMA(alo, qb0.h, acc);
        acc = MFMA(alo, qb0.l, acc);
        acc = MFMA(ahi, qb1.h, acc);
        acc = MFMA(ahi, qb1.l, acc);
        const int kq = k0 + nt * 16 + lg * 4;
        const float4 c = B.p[nt];
        float cv[4] = {c.x, c.y, c.z, c.w};
        float ov[4];
#pragma unroll
        for (int r = 0; r < 4; ++r) {
            float e = (kq + r < KE) ? __expf(cv[r] + acc[r] * SCALE) : 0.f;
            ov[r] = e;
            lsum += e;
        }
        float4 o;
        o.x = ov[0]; o.y = ov[1]; o.z = ov[2]; o.w = ov[3];
        *reinterpret_cast<float4*>(prow + kq) = o;
    }
}

// ---------------- K2a: per (q, 256-k slice): rel MFMA + exp, unnormalized e,
// partial row sums -> ws[ksl][q][bh].
__global__ __launch_bounds__(256) void k_rel_exp(const float* __restrict__ query,
                                                 const float* __restrict__ bigr_k,
                                                 float* __restrict__ P,
                                                 float* __restrict__ partial) {
    const int ksl = blockIdx.x;
    const int qpos = SQ - 1 - (int)blockIdx.y;  // big rows first
    const int tid = threadIdx.x;
    const int w = tid >> 6, l = tid & 63;
    const int lm = l & 15, lg = l >> 4;
    const int bh = w * 16 + lm;
    const int KE = qpos + 1;
    const int kbase = ksl * 256;
    float* pp = partial + ((size_t)ksl * SQ + qpos) * 64;
    if (kbase >= KE) {
        if (tid < 64) pp[tid] = 0.f;
        return;
    }
    const float* qrow = query + ((size_t)bh * SQ + qpos) * DH + lg * 8;
    Frag2 qb0 = load_split(qrow);
    Frag2 qb1 = load_split(qrow + 32);
    const float* bk = bigr_k + (size_t)qpos * SK * DH;
    float* prow = P + ((size_t)bh * SQ + qpos) * SK;

    const int nsteps = min(8, (KE - kbase + 31) >> 5);
    StepBuf b0, b1;
    k2_issue(kbase, bk, prow, lm, lg, b0);
    float lsum = 0.f;
#pragma unroll 1
    for (int s = 0; s < nsteps; s += 2) {
        const int kA = kbase + s * 32;
        k2_issue(min(kA + 32, SK - 32), bk, prow, lm, lg, b1);
        k2_compute(kA, b0, qb0, qb1, lg, KE, prow, lsum);
        k2_issue(min(kA + 64, SK - 32), bk, prow, lm, lg, b0);
        if (s + 1 < nsteps)
            k2_compute(kA + 32, b1, qb0, qb1, lg, KE, prow, lsum);
    }
    lsum += __shfl_xor(lsum, 16);
    lsum += __shfl_xor(lsum, 32);
    if (l < 16) pp[w * 16 + l] = lsum;
}

// ---------------- K3: out = (1/sum) * e @ V ; normalizes P in place as it streams.
__global__ __launch_bounds__(256) void k_pv(float* __restrict__ P,
                                            const float* __restrict__ V,
                                            const float* __restrict__ partial,
                                            float* __restrict__ out) {
    const int qt = 15 - (int)blockIdx.x;  // big tiles first
    const int bh = blockIdx.y;
    const int tid = threadIdx.x;
    const int w = tid >> 6, l = tid & 63;
    const int lm = l & 15, lg = l >> 4;
    const int q0 = qt * 64 + w * 16;

    float wrecip;
    {
        const size_t b = (size_t)(q0 + lm) * 64 + bh;
        float s = partial[b] + partial[(size_t)SQ * 64 + b] +
                  partial[(size_t)2 * SQ * 64 + b] + partial[(size_t)3 * SQ * 64 + b];
        wrecip = 1.0f / s;
    }
    float orecip[4];
#pragma unroll
    for (int r = 0; r < 4; ++r) {
        const size_t b = (size_t)(q0 + lg * 4 + r) * 64 + bh;
        float s = partial[b] + partial[(size_t)SQ * 64 + b] +
                  partial[(size_t)2 * SQ * 64 + b] + partial[(size_t)3 * SQ * 64 + b];
        orecip[r] = 1.0f / s;
    }

    f32x4 acc[4] = {{0.f,0.f,0.f,0.f},{0.f,0.f,0.f,0.f},{0.f,0.f,0.f,0.f},{0.f,0.f,0.f,0.f}};
    const int kend = q0 + 16;
    for (int k0 = 0; k0 < kend; k0 += 32) {
        float* arow = P + ((size_t)bh * SQ + q0 + lm) * SK + k0 + lg * 8;
        float4 x0 = *reinterpret_cast<const float4*>(arow);
        float4 x1 = *reinterpret_cast<const float4*>(arow + 4);
        float4 y0 = {x0.x * wrecip, x0.y * wrecip, x0.z * wrecip, x0.w * wrecip};
        float4 y1 = {x1.x * wrecip, x1.y * wrecip, x1.z * wrecip, x1.w * wrecip};
        *reinterpret_cast<float4*>(arow) = y0;
        *reinterpret_cast<float4*>(arow + 4) = y1;
        bf16x8 a = pack_bf8(x0, x1);
#pragma unroll
        for (int nt = 0; nt < 4; ++nt) {
            const float* bcol = V + ((size_t)bh * SK + k0 + lg * 8) * DH + nt * 16 + lm;
            bf16x8 b = load_bf8_strided(bcol, DH);
            acc[nt] = MFMA(a, b, acc[nt]);
        }
    }
#pragma unroll
    for (int nt = 0; nt < 4; ++nt)
#pragma unroll
        for (int r = 0; r < 4; ++r)
            out[((size_t)bh * SQ + q0 + lg * 4 + r) * DH + nt * 16 + lm] =
                acc[nt][r] * orecip[r];
}

// ---------------- K4: out += P_norm @ bigr_v[q]; LDS double-buffered, 1 sync/step.
__global__ __launch_bounds__(256) void k_pr(const float* __restrict__ P,
                                            const float* __restrict__ bigr_v,
                                            float* __restrict__ out) {
    __shared__ float vt[2][64][33];  // [buf][d][k] transposed tile
    const int qpos = SQ - 1 - (int)blockIdx.x;
    const int tid = threadIdx.x;
    const int w = tid >> 6, l = tid & 63;
    const int lm = l & 15, lg = l >> 4;
    const int bh0 = w * 16;
    const int skk = tid & 31, sdd = (tid >> 5) * 8;
    const float* bv = bigr_v + (size_t)qpos * SK * DH;
    const float* prow0 = P + ((size_t)(bh0 + lm) * SQ + qpos) * SK + lg * 8;
    f32x4 acc[4] = {{0.f,0.f,0.f,0.f},{0.f,0.f,0.f,0.f},{0.f,0.f,0.f,0.f},{0.f,0.f,0.f,0.f}};
    const int kend = qpos + 1;

    // preload first bigr_v tile + first P fragment
    float4 r0, r1, pa0, pa1;
    {
        const float* src = bv + (size_t)skk * DH + sdd;
        r0 = *reinterpret_cast<const float4*>(src);
        r1 = *reinterpret_cast<const float4*>(src + 4);
        pa0 = *reinterpret_cast<const float4*>(prow0);
        pa1 = *reinterpret_cast<const float4*>(prow0 + 4);
    }
    int cur = 0;
#pragma unroll 1
    for (int k0 = 0; k0 < kend; k0 += 32) {
        // write staged regs into vt[cur]
        vt[cur][sdd + 0][skk] = r0.x; vt[cur][sdd + 1][skk] = r0.y;
        vt[cur][sdd + 2][skk] = r0.z; vt[cur][sdd + 3][skk] = r0.w;
        vt[cur][sdd + 4][skk] = r1.x; vt[cur][sdd + 5][skk] = r1.y;
        vt[cur][sdd + 6][skk] = r1.z; vt[cur][sdd + 7][skk] = r1.w;
        __syncthreads();
        // issue next tile (bigr_v + P) into regs (clamped; extra loads benign)
        {
            const int kn = min(k0 + 32, SK - 32);
            const float* src = bv + (size_t)(kn + skk) * DH + sdd;
            r0 = *reinterpret_cast<const float4*>(src);
            r1 = *reinterpret_cast<const float4*>(src + 4);
        }
        bf16x8 a = pack_bf8(pa0, pa1);
        {
            const int kn = min(k0 + 32, SK - 32);
            pa0 = *reinterpret_cast<const float4*>(prow0 + kn);
            pa1 = *reinterpret_cast<const float4*>(prow0 + kn + 4);
        }
#pragma unroll
        for (int nt = 0; nt < 4; ++nt) {
            const float* bp = &vt[cur][nt * 16 + lm][lg * 8];
            float4 u0 = *reinterpret_cast<const float4*>(bp);
            float4 u1 = *reinterpret_cast<const float4*>(bp + 4);
            acc[nt] = MFMA(a, pack_bf8(u0, u1), acc[nt]);
        }
        cur ^= 1;
    }
#pragma unroll
    for (int nt = 0; nt < 4; ++nt)
#pragma unroll
        for (int r = 0; r < 4; ++r) {
            const size_t o = ((size_t)(bh0 + lg * 4 + r) * SQ + qpos) * DH + nt * 16 + lm;
            out[o] += acc[nt][r];
        }
}

extern "C" void kernel_launch(void* const* d_in, const int* in_sizes, int n_in,
                              void* d_out, int out_size, void* d_ws, size_t ws_size,
                              hipStream_t stream) {
    const float* query  = (const float*)d_in[0];
    const float* key    = (const float*)d_in[1];
    const float* value  = (const float*)d_in[2];
    const float* bigr_k = (const float*)d_in[3];
    const float* bigr_v = (const float*)d_in[4];
    float* out = (float*)d_out;                       // BH*SQ*DH
    float* P   = out + (size_t)BH * SQ * DH;          // BH*SQ*SK
    float* partial = (float*)d_ws;                    // [4][SQ][BH] fp32 = 1 MB

    k_scores<<<dim3(16, 16, BH), 256, 0, stream>>>(query, key, P);
    k_rel_exp<<<dim3(4, SQ), 256, 0, stream>>>(query, bigr_k, P, partial);
    k_pv<<<dim3(16, BH), 256, 0, stream>>>(P, value, partial, out);
    k_pr<<<dim3(SQ), 256, 0, stream>>>(P, bigr_v, out);
}

// Round 5
// 604.595 us; speedup vs baseline: 1.0574x; 1.0574x over previous
//
#include <hip/hip_runtime.h>
#include <hip/hip_bf16.h>

// Relative-position causal attention, B=4 H=16 Q=K=1024 D=64 (fp32 in/out).
// d_out = [output (BH*Q*D) | p_attn (BH*Q*K)] fp32.
// K1 content scores -> K2a rel + exp (waves split k-range: each wave owns 64
// k-rows x all 64 bh; bigr_k loaded exactly once) -> K3 P@V (normalizes P in
// place) -> K4 P@bigr_v (LDS double-buffered).

#define BH 64
#define SQ 1024
#define SK 1024
#define DH 64
#define SCALE 0.125f

typedef __attribute__((ext_vector_type(4))) float f32x4;
typedef __attribute__((ext_vector_type(8))) unsigned short ushort8;
typedef __attribute__((ext_vector_type(8))) __bf16 bf16x8;

static __device__ inline unsigned short f2bf(float x) {
    unsigned u = __float_as_uint(x);
    unsigned r = u + 0x7FFFu + ((u >> 16) & 1u);
    return (unsigned short)(r >> 16);
}
static __device__ inline float bf2f(unsigned short s) {
    return __uint_as_float(((unsigned)s) << 16);
}

struct Frag2 { bf16x8 h, l; };

static __device__ inline Frag2 load_split(const float* __restrict__ p) {
    float4 x0 = *reinterpret_cast<const float4*>(p);
    float4 x1 = *reinterpret_cast<const float4*>(p + 4);
    float v[8] = {x0.x, x0.y, x0.z, x0.w, x1.x, x1.y, x1.z, x1.w};
    ushort8 uh, ul;
#pragma unroll
    for (int j = 0; j < 8; ++j) {
        unsigned short h = f2bf(v[j]);
        float r = v[j] - bf2f(h);
        uh[j] = h;
        ul[j] = f2bf(r);
    }
    Frag2 f;
    f.h = __builtin_bit_cast(bf16x8, uh);
    f.l = __builtin_bit_cast(bf16x8, ul);
    return f;
}

static __device__ inline bf16x8 pack_bf8(float4 x0, float4 x1) {
    float v[8] = {x0.x, x0.y, x0.z, x0.w, x1.x, x1.y, x1.z, x1.w};
    ushort8 u;
#pragma unroll
    for (int j = 0; j < 8; ++j) u[j] = f2bf(v[j]);
    return __builtin_bit_cast(bf16x8, u);
}

static __device__ inline bf16x8 load_bf8(const float* __restrict__ p) {
    float4 x0 = *reinterpret_cast<const float4*>(p);
    float4 x1 = *reinterpret_cast<const float4*>(p + 4);
    return pack_bf8(x0, x1);
}

static __device__ inline bf16x8 load_bf8_strided(const float* __restrict__ p, int stride) {
    ushort8 u;
#pragma unroll
    for (int j = 0; j < 8; ++j) u[j] = f2bf(p[(size_t)j * stride]);
    return __builtin_bit_cast(bf16x8, u);
}

#define MFMA(a, b, c) __builtin_amdgcn_mfma_f32_16x16x32_bf16((a), (b), (c), 0, 0, 0)

static __device__ inline f32x4 mfma_split(const Frag2& a, const Frag2& b, f32x4 c) {
    c = MFMA(a.h, b.h, c);
    c = MFMA(a.h, b.l, c);
    c = MFMA(a.l, b.h, c);
    return c;
}

// ---------------- K1: content scores Q@K^T * scale -> P region (zeros above diag)
__global__ __launch_bounds__(256) void k_scores(const float* __restrict__ q,
                                                const float* __restrict__ k,
                                                float* __restrict__ P) {
    const int kt = blockIdx.x, qt = blockIdx.y, bh = blockIdx.z;
    const int tid = threadIdx.x;
    const int kbase = kt * 64;
    if (kbase > qt * 64 + 63) {  // fully masked tile: zeros
        const int row = qt * 64 + (tid >> 2);
        float4 z = {0.f, 0.f, 0.f, 0.f};
        float4* dst = reinterpret_cast<float4*>(
            &P[((size_t)bh * SQ + row) * SK + kbase + (tid & 3) * 16]);
        dst[0] = z; dst[1] = z; dst[2] = z; dst[3] = z;
        return;
    }
    const int w = tid >> 6, l = tid & 63;
    const int lm = l & 15, lg = l >> 4;
    const int q0 = qt * 64 + w * 16;
    const float* qrow = q + ((size_t)bh * SQ + q0 + lm) * DH + lg * 8;
    Frag2 a0 = load_split(qrow);
    Frag2 a1 = load_split(qrow + 32);
#pragma unroll
    for (int nt = 0; nt < 4; ++nt) {
        const int kc = kbase + nt * 16 + lm;
        f32x4 acc = {0.f, 0.f, 0.f, 0.f};
        if (kbase + nt * 16 <= q0 + 15) {
            const float* krow = k + ((size_t)bh * SK + kc) * DH + lg * 8;
            Frag2 b0 = load_split(krow);
            Frag2 b1 = load_split(krow + 32);
            acc = mfma_split(a0, b0, acc);
            acc = mfma_split(a1, b1, acc);
        }
#pragma unroll
        for (int r = 0; r < 4; ++r) {
            const int qq = q0 + lg * 4 + r;
            float v = (kc <= qq) ? acc[r] * SCALE : 0.f;
            P[((size_t)bh * SQ + qq) * SK + kc] = v;
        }
    }
}

// ---------------- K2a: per (q, 256-k slice); wave w owns k-rows [kw, kw+64).
// Each wave computes all 64 bh columns: A = bigr_k rows (single bf16),
// B = query bh-tiles (split bf16). C lane map: bh = nt*16+lm, k = k0+lg*4+r.
struct SB { float4 a[4]; float4 p[4]; };

static __device__ inline void k2r_issue(SB& B, int k0, const float* __restrict__ bk,
                                        float* const* prow, int lm, int lg) {
    const float* arow = bk + (size_t)(k0 + lm) * DH + lg * 8;
    B.a[0] = *reinterpret_cast<const float4*>(arow);
    B.a[1] = *reinterpret_cast<const float4*>(arow + 4);
    B.a[2] = *reinterpret_cast<const float4*>(arow + 32);
    B.a[3] = *reinterpret_cast<const float4*>(arow + 36);
#pragma unroll
    for (int nt = 0; nt < 4; ++nt)
        B.p[nt] = *reinterpret_cast<const float4*>(prow[nt] + k0 + lg * 4);
}

static __device__ inline void k2r_compute(const SB& B, int k0,
                                          const Frag2* qh0, const Frag2* qh1,
                                          float* const* prow, int lg, int KE,
                                          float* lsum) {
    bf16x8 alo = pack_bf8(B.a[0], B.a[1]);
    bf16x8 ahi = pack_bf8(B.a[2], B.a[3]);
    const int kq = k0 + lg * 4;
#pragma unroll
    for (int nt = 0; nt < 4; ++nt) {
        f32x4 acc = {0.f, 0.f, 0.f, 0.f};
        acc = MFMA(alo, qh0[nt].h, acc);
        acc = MFMA(alo, qh0[nt].l, acc);
        acc = MFMA(ahi, qh1[nt].h, acc);
        acc = MFMA(ahi, qh1[nt].l, acc);
        const float4 c = B.p[nt];
        float cv[4] = {c.x, c.y, c.z, c.w};
        float ov[4];
#pragma unroll
        for (int r = 0; r < 4; ++r) {
            float e = (kq + r < KE) ? __expf(cv[r] + acc[r] * SCALE) : 0.f;
            ov[r] = e;
            lsum[nt] += e;
        }
        float4 o;
        o.x = ov[0]; o.y = ov[1]; o.z = ov[2]; o.w = ov[3];
        *reinterpret_cast<float4*>(prow[nt] + kq) = o;
    }
}

__global__ __launch_bounds__(256) void k_rel_exp(const float* __restrict__ query,
                                                 const float* __restrict__ bigr_k,
                                                 float* __restrict__ P,
                                                 float* __restrict__ partial) {
    __shared__ float red[4][64];
    const int ksl = blockIdx.x;
    const int qpos = SQ - 1 - (int)blockIdx.y;  // big rows first
    const int tid = threadIdx.x;
    const int w = tid >> 6, l = tid & 63;
    const int lm = l & 15, lg = l >> 4;
    const int KE = qpos + 1;
    float* pp = partial + ((size_t)ksl * SQ + qpos) * 64;
    if (ksl * 256 >= KE) {  // whole slice masked
        if (tid < 64) pp[tid] = 0.f;
        return;
    }
    const int kw = ksl * 256 + w * 64;  // this wave's chunk

    // B fragments: query rows bh = nt*16+lm (all 64 bh), split bf16
    Frag2 qh0[4], qh1[4];
    float* prow[4];
#pragma unroll
    for (int nt = 0; nt < 4; ++nt) {
        const int bh = nt * 16 + lm;
        const float* qrow = query + ((size_t)bh * SQ + qpos) * DH + lg * 8;
        qh0[nt] = load_split(qrow);
        qh1[nt] = load_split(qrow + 32);
        prow[nt] = P + ((size_t)bh * SQ + qpos) * SK;
    }

    float lsum[4] = {0.f, 0.f, 0.f, 0.f};
    const int rem = KE - kw;
    const int nst = (rem <= 0) ? 0 : min(4, (rem + 15) >> 4);
    const float* bk = bigr_k + (size_t)qpos * SK * DH;

    SB b0, b1;
    if (nst > 0) {
        k2r_issue(b0, kw, bk, prow, lm, lg);
        if (nst > 1) k2r_issue(b1, kw + 16, bk, prow, lm, lg);
        k2r_compute(b0, kw, qh0, qh1, prow, lg, KE, lsum);
        if (nst > 1) {
            if (nst > 2) k2r_issue(b0, kw + 32, bk, prow, lm, lg);
            k2r_compute(b1, kw + 16, qh0, qh1, prow, lg, KE, lsum);
        }
        if (nst > 2) {
            if (nst > 3) k2r_issue(b1, kw + 48, bk, prow, lm, lg);
            k2r_compute(b0, kw + 32, qh0, qh1, prow, lg, KE, lsum);
        }
        if (nst > 3) k2r_compute(b1, kw + 48, qh0, qh1, prow, lg, KE, lsum);
    }

    // reduce lane sums (lg axis) -> per-bh sums, then across waves via LDS
#pragma unroll
    for (int nt = 0; nt < 4; ++nt) {
        float s = lsum[nt];
        s += __shfl_xor(s, 16);
        s += __shfl_xor(s, 32);
        lsum[nt] = s;
    }
    if (l < 16) {
#pragma unroll
        for (int nt = 0; nt < 4; ++nt) red[w][nt * 16 + l] = lsum[nt];
    }
    __syncthreads();
    if (tid < 64)
        pp[tid] = red[0][tid] + red[1][tid] + red[2][tid] + red[3][tid];
}

// ---------------- K3: out = (1/sum) * e @ V ; normalizes P in place as it streams.
__global__ __launch_bounds__(256) void k_pv(float* __restrict__ P,
                                            const float* __restrict__ V,
                                            const float* __restrict__ partial,
                                            float* __restrict__ out) {
    const int qt = 15 - (int)blockIdx.x;  // big tiles first
    const int bh = blockIdx.y;
    const int tid = threadIdx.x;
    const int w = tid >> 6, l = tid & 63;
    const int lm = l & 15, lg = l >> 4;
    const int q0 = qt * 64 + w * 16;

    float wrecip;
    {
        const size_t b = (size_t)(q0 + lm) * 64 + bh;
        float s = partial[b] + partial[(size_t)SQ * 64 + b] +
                  partial[(size_t)2 * SQ * 64 + b] + partial[(size_t)3 * SQ * 64 + b];
        wrecip = 1.0f / s;
    }
    float orecip[4];
#pragma unroll
    for (int r = 0; r < 4; ++r) {
        const size_t b = (size_t)(q0 + lg * 4 + r) * 64 + bh;
        float s = partial[b] + partial[(size_t)SQ * 64 + b] +
                  partial[(size_t)2 * SQ * 64 + b] + partial[(size_t)3 * SQ * 64 + b];
        orecip[r] = 1.0f / s;
    }

    f32x4 acc[4] = {{0.f,0.f,0.f,0.f},{0.f,0.f,0.f,0.f},{0.f,0.f,0.f,0.f},{0.f,0.f,0.f,0.f}};
    const int kend = q0 + 16;
    for (int k0 = 0; k0 < kend; k0 += 32) {
        float* arow = P + ((size_t)bh * SQ + q0 + lm) * SK + k0 + lg * 8;
        float4 x0 = *reinterpret_cast<const float4*>(arow);
        float4 x1 = *reinterpret_cast<const float4*>(arow + 4);
        float4 y0 = {x0.x * wrecip, x0.y * wrecip, x0.z * wrecip, x0.w * wrecip};
        float4 y1 = {x1.x * wrecip, x1.y * wrecip, x1.z * wrecip, x1.w * wrecip};
        *reinterpret_cast<float4*>(arow) = y0;
        *reinterpret_cast<float4*>(arow + 4) = y1;
        bf16x8 a = pack_bf8(x0, x1);
#pragma unroll
        for (int nt = 0; nt < 4; ++nt) {
            const float* bcol = V + ((size_t)bh * SK + k0 + lg * 8) * DH + nt * 16 + lm;
            bf16x8 b = load_bf8_strided(bcol, DH);
            acc[nt] = MFMA(a, b, acc[nt]);
        }
    }
#pragma unroll
    for (int nt = 0; nt < 4; ++nt)
#pragma unroll
        for (int r = 0; r < 4; ++r)
            out[((size_t)bh * SQ + q0 + lg * 4 + r) * DH + nt * 16 + lm] =
                acc[nt][r] * orecip[r];
}

// ---------------- K4: out += P_norm @ bigr_v[q]; LDS double-buffered, 1 sync/step.
__global__ __launch_bounds__(256) void k_pr(const float* __restrict__ P,
                                            const float* __restrict__ bigr_v,
                                            float* __restrict__ out) {
    __shared__ float vt[2][64][33];  // [buf][d][k] transposed tile
    const int qpos = SQ - 1 - (int)blockIdx.x;
    const int tid = threadIdx.x;
    const int w = tid >> 6, l = tid & 63;
    const int lm = l & 15, lg = l >> 4;
    const int bh0 = w * 16;
    const int skk = tid & 31, sdd = (tid >> 5) * 8;
    const float* bv = bigr_v + (size_t)qpos * SK * DH;
    const float* prow0 = P + ((size_t)(bh0 + lm) * SQ + qpos) * SK + lg * 8;
    f32x4 acc[4] = {{0.f,0.f,0.f,0.f},{0.f,0.f,0.f,0.f},{0.f,0.f,0.f,0.f},{0.f,0.f,0.f,0.f}};
    const int kend = qpos + 1;

    float4 r0, r1, pa0, pa1;
    {
        const float* src = bv + (size_t)skk * DH + sdd;
        r0 = *reinterpret_cast<const float4*>(src);
        r1 = *reinterpret_cast<const float4*>(src + 4);
        pa0 = *reinterpret_cast<const float4*>(prow0);
        pa1 = *reinterpret_cast<const float4*>(prow0 + 4);
    }
    int cur = 0;
#pragma unroll 1
    for (int k0 = 0; k0 < kend; k0 += 32) {
        vt[cur][sdd + 0][skk] = r0.x; vt[cur][sdd + 1][skk] = r0.y;
        vt[cur][sdd + 2][skk] = r0.z; vt[cur][sdd + 3][skk] = r0.w;
        vt[cur][sdd + 4][skk] = r1.x; vt[cur][sdd + 5][skk] = r1.y;
        vt[cur][sdd + 6][skk] = r1.z; vt[cur][sdd + 7][skk] = r1.w;
        __syncthreads();
        {
            const int kn = min(k0 + 32, SK - 32);
            const float* src = bv + (size_t)(kn + skk) * DH + sdd;
            r0 = *reinterpret_cast<const float4*>(src);
            r1 = *reinterpret_cast<const float4*>(src + 4);
        }
        bf16x8 a = pack_bf8(pa0, pa1);
        {
            const int kn = min(k0 + 32, SK - 32);
            pa0 = *reinterpret_cast<const float4*>(prow0 + kn);
            pa1 = *reinterpret_cast<const float4*>(prow0 + kn + 4);
        }
#pragma unroll
        for (int nt = 0; nt < 4; ++nt) {
            const float* bp = &vt[cur][nt * 16 + lm][lg * 8];
            float4 u0 = *reinterpret_cast<const float4*>(bp);
            float4 u1 = *reinterpret_cast<const float4*>(bp + 4);
            acc[nt] = MFMA(a, pack_bf8(u0, u1), acc[nt]);
        }
        cur ^= 1;
    }
#pragma unroll
    for (int nt = 0; nt < 4; ++nt)
#pragma unroll
        for (int r = 0; r < 4; ++r) {
            const size_t o = ((size_t)(bh0 + lg * 4 + r) * SQ + qpos) * DH + nt * 16 + lm;
            out[o] += acc[nt][r];
        }
}

extern "C" void kernel_launch(void* const* d_in, const int* in_sizes, int n_in,
                              void* d_out, int out_size, void* d_ws, size_t ws_size,
                              hipStream_t stream) {
    const float* query  = (const float*)d_in[0];
    const float* key    = (const float*)d_in[1];
    const float* value  = (const float*)d_in[2];
    const float* bigr_k = (const float*)d_in[3];
    const float* bigr_v = (const float*)d_in[4];
    float* out = (float*)d_out;                       // BH*SQ*DH
    float* P   = out + (size_t)BH * SQ * DH;          // BH*SQ*SK
    float* partial = (float*)d_ws;                    // [4][SQ][BH] fp32 = 1 MB

    k_scores<<<dim3(16, 16, BH), 256, 0, stream>>>(query, key, P);
    k_rel_exp<<<dim3(4, SQ), 256, 0, stream>>>(query, bigr_k, P, partial);
    k_pv<<<dim3(16, BH), 256, 0, stream>>>(P, value, partial, out);
    k_pr<<<dim3(SQ), 256, 0, stream>>>(P, bigr_v, out);
}

// Round 6
// 591.670 us; speedup vs baseline: 1.0805x; 1.0218x over previous
//
#include <hip/hip_runtime.h>
#include <hip/hip_bf16.h>

// Relative-position causal attention, B=4 H=16 Q=K=1024 D=64 (fp32 in/out).
// d_out = [output (BH*Q*D) | p_attn (BH*Q*K)] fp32.
// K1 content scores -> K2 rel+exp (block = 256-k-slice x 8-q tile; each wave owns
// 2 q rows, 32 k-steps, reg double-buffer, no syncs) -> K3 P@V (normalizes P in
// place) -> K4 P@bigr_v (R2-style LDS staging).

#define BH 64
#define SQ 1024
#define SK 1024
#define DH 64
#define SCALE 0.125f

typedef __attribute__((ext_vector_type(4))) float f32x4;
typedef __attribute__((ext_vector_type(8))) unsigned short ushort8;
typedef __attribute__((ext_vector_type(8))) __bf16 bf16x8;

static __device__ inline unsigned short f2bf(float x) {
    unsigned u = __float_as_uint(x);
    unsigned r = u + 0x7FFFu + ((u >> 16) & 1u);
    return (unsigned short)(r >> 16);
}
static __device__ inline float bf2f(unsigned short s) {
    return __uint_as_float(((unsigned)s) << 16);
}

struct Frag2 { bf16x8 h, l; };

static __device__ inline Frag2 load_split(const float* __restrict__ p) {
    float4 x0 = *reinterpret_cast<const float4*>(p);
    float4 x1 = *reinterpret_cast<const float4*>(p + 4);
    float v[8] = {x0.x, x0.y, x0.z, x0.w, x1.x, x1.y, x1.z, x1.w};
    ushort8 uh, ul;
#pragma unroll
    for (int j = 0; j < 8; ++j) {
        unsigned short h = f2bf(v[j]);
        float r = v[j] - bf2f(h);
        uh[j] = h;
        ul[j] = f2bf(r);
    }
    Frag2 f;
    f.h = __builtin_bit_cast(bf16x8, uh);
    f.l = __builtin_bit_cast(bf16x8, ul);
    return f;
}

static __device__ inline bf16x8 pack_bf8(float4 x0, float4 x1) {
    float v[8] = {x0.x, x0.y, x0.z, x0.w, x1.x, x1.y, x1.z, x1.w};
    ushort8 u;
#pragma unroll
    for (int j = 0; j < 8; ++j) u[j] = f2bf(v[j]);
    return __builtin_bit_cast(bf16x8, u);
}

static __device__ inline bf16x8 load_bf8(const float* __restrict__ p) {
    float4 x0 = *reinterpret_cast<const float4*>(p);
    float4 x1 = *reinterpret_cast<const float4*>(p + 4);
    return pack_bf8(x0, x1);
}

static __device__ inline bf16x8 load_bf8_strided(const float* __restrict__ p, int stride) {
    ushort8 u;
#pragma unroll
    for (int j = 0; j < 8; ++j) u[j] = f2bf(p[(size_t)j * stride]);
    return __builtin_bit_cast(bf16x8, u);
}

#define MFMA(a, b, c) __builtin_amdgcn_mfma_f32_16x16x32_bf16((a), (b), (c), 0, 0, 0)

static __device__ inline f32x4 mfma_split(const Frag2& a, const Frag2& b, f32x4 c) {
    c = MFMA(a.h, b.h, c);
    c = MFMA(a.h, b.l, c);
    c = MFMA(a.l, b.h, c);
    return c;
}

// ---------------- K1: content scores Q@K^T * scale -> P region (zeros above diag)
__global__ __launch_bounds__(256) void k_scores(const float* __restrict__ q,
                                                const float* __restrict__ k,
                                                float* __restrict__ P) {
    const int kt = blockIdx.x, qt = blockIdx.y, bh = blockIdx.z;
    const int tid = threadIdx.x;
    const int kbase = kt * 64;
    if (kbase > qt * 64 + 63) {  // fully masked tile: zeros
        const int row = qt * 64 + (tid >> 2);
        float4 z = {0.f, 0.f, 0.f, 0.f};
        float4* dst = reinterpret_cast<float4*>(
            &P[((size_t)bh * SQ + row) * SK + kbase + (tid & 3) * 16]);
        dst[0] = z; dst[1] = z; dst[2] = z; dst[3] = z;
        return;
    }
    const int w = tid >> 6, l = tid & 63;
    const int lm = l & 15, lg = l >> 4;
    const int q0 = qt * 64 + w * 16;
    const float* qrow = q + ((size_t)bh * SQ + q0 + lm) * DH + lg * 8;
    Frag2 a0 = load_split(qrow);
    Frag2 a1 = load_split(qrow + 32);
#pragma unroll
    for (int nt = 0; nt < 4; ++nt) {
        const int kc = kbase + nt * 16 + lm;
        f32x4 acc = {0.f, 0.f, 0.f, 0.f};
        if (kbase + nt * 16 <= q0 + 15) {
            const float* krow = k + ((size_t)bh * SK + kc) * DH + lg * 8;
            Frag2 b0 = load_split(krow);
            Frag2 b1 = load_split(krow + 32);
            acc = mfma_split(a0, b0, acc);
            acc = mfma_split(a1, b1, acc);
        }
#pragma unroll
        for (int r = 0; r < 4; ++r) {
            const int qq = q0 + lg * 4 + r;
            float v = (kc <= qq) ? acc[r] * SCALE : 0.f;
            P[((size_t)bh * SQ + qq) * SK + kc] = v;
        }
    }
}

// ---------------- K2: block = (256-k slice, 8-q tile); wave owns q = qbase+i*4+w.
// A = bigr_k k-rows (single bf16), B = query bh-cols (split bf16).
// C lane map: k = k0+lg*4+r, bh = nt*16+lm. 16 k-steps per q, reg double-buffer.
struct SB { float4 a[4]; float4 p[4]; };

static __device__ inline void k2_issue(SB& B, const float* __restrict__ bk,
                                       float* const* prow, int k0, int lm, int lg) {
    const float* arow = bk + (size_t)(k0 + lm) * DH + lg * 8;
    B.a[0] = *reinterpret_cast<const float4*>(arow);
    B.a[1] = *reinterpret_cast<const float4*>(arow + 4);
    B.a[2] = *reinterpret_cast<const float4*>(arow + 32);
    B.a[3] = *reinterpret_cast<const float4*>(arow + 36);
#pragma unroll
    for (int nt = 0; nt < 4; ++nt)
        B.p[nt] = *reinterpret_cast<const float4*>(prow[nt] + k0 + lg * 4);
}

static __device__ inline void k2_compute(const SB& B, const Frag2* qh0, const Frag2* qh1,
                                         float* const* prow, int k0, int lg, int KE,
                                         float* lsum) {
    bf16x8 alo = pack_bf8(B.a[0], B.a[1]);
    bf16x8 ahi = pack_bf8(B.a[2], B.a[3]);
    const int kq = k0 + lg * 4;
#pragma unroll
    for (int nt = 0; nt < 4; ++nt) {
        f32x4 acc = {0.f, 0.f, 0.f, 0.f};
        acc = MFMA(alo, qh0[nt].h, acc);
        acc = MFMA(alo, qh0[nt].l, acc);
        acc = MFMA(ahi, qh1[nt].h, acc);
        acc = MFMA(ahi, qh1[nt].l, acc);
        const float4 c = B.p[nt];
        float cv[4] = {c.x, c.y, c.z, c.w};
        float ov[4];
#pragma unroll
        for (int r = 0; r < 4; ++r) {
            float e = (kq + r < KE) ? __expf(cv[r] + acc[r] * SCALE) : 0.f;
            ov[r] = e;
            lsum[nt] += e;
        }
        float4 o;
        o.x = ov[0]; o.y = ov[1]; o.z = ov[2]; o.w = ov[3];
        *reinterpret_cast<float4*>(prow[nt] + kq) = o;
    }
}

__global__ __launch_bounds__(256) void k_rel_exp(const float* __restrict__ query,
                                                 const float* __restrict__ bigr_k,
                                                 float* __restrict__ P,
                                                 float* __restrict__ partial) {
    const int ksl = blockIdx.x;
    const int qbase = SQ - 8 - (int)blockIdx.y * 8;  // big q first
    const int kbase = ksl * 256;
    const int tid = threadIdx.x;
    const int w = tid >> 6, l = tid & 63;
    const int lm = l & 15, lg = l >> 4;

#pragma unroll 1
    for (int i = 0; i < 2; ++i) {
        const int q = qbase + i * 4 + w;
        const int KE = q + 1;
        float* pp = partial + ((size_t)ksl * SQ + q) * 64;
        if (kbase >= KE) {  // this q fully masked in this slice
            if (l < 16) {
#pragma unroll
                for (int nt = 0; nt < 4; ++nt) pp[nt * 16 + l] = 0.f;
            }
            continue;
        }
        Frag2 qh0[4], qh1[4];
        float* prow[4];
#pragma unroll
        for (int nt = 0; nt < 4; ++nt) {
            const int bh = nt * 16 + lm;
            const float* qrow = query + ((size_t)bh * SQ + q) * DH + lg * 8;
            qh0[nt] = load_split(qrow);
            qh1[nt] = load_split(qrow + 32);
            prow[nt] = P + ((size_t)bh * SQ + q) * SK;
        }
        const float* bk = bigr_k + (size_t)q * SK * DH;
        const int keff = min(KE - kbase, 256);
        const int nks = (keff + 15) >> 4;
        float lsum[4] = {0.f, 0.f, 0.f, 0.f};
        SB b0, b1;
        k2_issue(b0, bk, prow, kbase, lm, lg);
        int s = 0;
#pragma unroll 1
        for (; s + 1 < nks; s += 2) {
            k2_issue(b1, bk, prow, kbase + (s + 1) * 16, lm, lg);
            k2_compute(b0, qh0, qh1, prow, kbase + s * 16, lg, KE, lsum);
            if (s + 2 < nks) k2_issue(b0, bk, prow, kbase + (s + 2) * 16, lm, lg);
            k2_compute(b1, qh0, qh1, prow, kbase + (s + 1) * 16, lg, KE, lsum);
        }
        if (s < nks) k2_compute(b0, qh0, qh1, prow, kbase + s * 16, lg, KE, lsum);
        // reduce over lg (xor 16, 32) -> per-bh sums; lanes l<16 write
#pragma unroll
        for (int nt = 0; nt < 4; ++nt) {
            float v = lsum[nt];
            v += __shfl_xor(v, 16);
            v += __shfl_xor(v, 32);
            lsum[nt] = v;
        }
        if (l < 16) {
#pragma unroll
            for (int nt = 0; nt < 4; ++nt) pp[nt * 16 + l] = lsum[nt];
        }
    }
}

// ---------------- K3: out = (1/sum) * e @ V ; normalizes P in place as it streams.
__global__ __launch_bounds__(256) void k_pv(float* __restrict__ P,
                                            const float* __restrict__ V,
                                            const float* __restrict__ partial,
                                            float* __restrict__ out) {
    const int qt = 15 - (int)blockIdx.x;  // big tiles first
    const int bh = blockIdx.y;
    const int tid = threadIdx.x;
    const int w = tid >> 6, l = tid & 63;
    const int lm = l & 15, lg = l >> 4;
    const int q0 = qt * 64 + w * 16;

    float wrecip;
    {
        const size_t b = (size_t)(q0 + lm) * 64 + bh;
        float s = partial[b] + partial[(size_t)SQ * 64 + b] +
                  partial[(size_t)2 * SQ * 64 + b] + partial[(size_t)3 * SQ * 64 + b];
        wrecip = 1.0f / s;
    }
    float orecip[4];
#pragma unroll
    for (int r = 0; r < 4; ++r) {
        const size_t b = (size_t)(q0 + lg * 4 + r) * 64 + bh;
        float s = partial[b] + partial[(size_t)SQ * 64 + b] +
                  partial[(size_t)2 * SQ * 64 + b] + partial[(size_t)3 * SQ * 64 + b];
        orecip[r] = 1.0f / s;
    }

    f32x4 acc[4] = {{0.f,0.f,0.f,0.f},{0.f,0.f,0.f,0.f},{0.f,0.f,0.f,0.f},{0.f,0.f,0.f,0.f}};
    const int kend = q0 + 16;
    for (int k0 = 0; k0 < kend; k0 += 32) {
        float* arow = P + ((size_t)bh * SQ + q0 + lm) * SK + k0 + lg * 8;
        float4 x0 = *reinterpret_cast<const float4*>(arow);
        float4 x1 = *reinterpret_cast<const float4*>(arow + 4);
        float4 y0 = {x0.x * wrecip, x0.y * wrecip, x0.z * wrecip, x0.w * wrecip};
        float4 y1 = {x1.x * wrecip, x1.y * wrecip, x1.z * wrecip, x1.w * wrecip};
        *reinterpret_cast<float4*>(arow) = y0;
        *reinterpret_cast<float4*>(arow + 4) = y1;
        bf16x8 a = pack_bf8(x0, x1);
#pragma unroll
        for (int nt = 0; nt < 4; ++nt) {
            const float* bcol = V + ((size_t)bh * SK + k0 + lg * 8) * DH + nt * 16 + lm;
            bf16x8 b = load_bf8_strided(bcol, DH);
            acc[nt] = MFMA(a, b, acc[nt]);
        }
    }
#pragma unroll
    for (int nt = 0; nt < 4; ++nt)
#pragma unroll
        for (int r = 0; r < 4; ++r)
            out[((size_t)bh * SQ + q0 + lg * 4 + r) * DH + nt * 16 + lm] =
                acc[nt][r] * orecip[r];
}

// ---------------- K4: out += P_norm @ bigr_v[q] (per q, all bh); R2-style LDS staging
__global__ __launch_bounds__(256) void k_pr(const float* __restrict__ P,
                                            const float* __restrict__ bigr_v,
                                            float* __restrict__ out) {
    __shared__ float vt[64][36];
    const int qpos = SQ - 1 - (int)blockIdx.x;
    const int tid = threadIdx.x;
    const int w = tid >> 6, l = tid & 63;
    const int lm = l & 15, lg = l >> 4;
    const int bh0 = w * 16;
    const int skk = tid & 31, sdd = (tid >> 5) * 8;
    f32x4 acc[4] = {{0.f,0.f,0.f,0.f},{0.f,0.f,0.f,0.f},{0.f,0.f,0.f,0.f},{0.f,0.f,0.f,0.f}};
    const int kend = qpos + 1;
    for (int k0 = 0; k0 < kend; k0 += 32) {
        __syncthreads();
        {
            const float* src = bigr_v + ((size_t)qpos * SK + k0 + skk) * DH + sdd;
            float4 v0 = *reinterpret_cast<const float4*>(src);
            float4 v1 = *reinterpret_cast<const float4*>(src + 4);
            vt[sdd + 0][skk] = v0.x; vt[sdd + 1][skk] = v0.y;
            vt[sdd + 2][skk] = v0.z; vt[sdd + 3][skk] = v0.w;
            vt[sdd + 4][skk] = v1.x; vt[sdd + 5][skk] = v1.y;
            vt[sdd + 6][skk] = v1.z; vt[sdd + 7][skk] = v1.w;
        }
        __syncthreads();
        const float* arow = P + ((size_t)(bh0 + lm) * SQ + qpos) * SK + k0 + lg * 8;
        bf16x8 a = load_bf8(arow);
#pragma unroll
        for (int nt = 0; nt < 4; ++nt) {
            const float* bp = &vt[nt * 16 + lm][lg * 8];
            float4 u0 = *reinterpret_cast<const float4*>(bp);
            float4 u1 = *reinterpret_cast<const float4*>(bp + 4);
            acc[nt] = MFMA(a, pack_bf8(u0, u1), acc[nt]);
        }
    }
#pragma unroll
    for (int nt = 0; nt < 4; ++nt)
#pragma unroll
        for (int r = 0; r < 4; ++r) {
            const size_t o = ((size_t)(bh0 + lg * 4 + r) * SQ + qpos) * DH + nt * 16 + lm;
            out[o] += acc[nt][r];
        }
}

extern "C" void kernel_launch(void* const* d_in, const int* in_sizes, int n_in,
                              void* d_out, int out_size, void* d_ws, size_t ws_size,
                              hipStream_t stream) {
    const float* query  = (const float*)d_in[0];
    const float* key    = (const float*)d_in[1];
    const float* value  = (const float*)d_in[2];
    const float* bigr_k = (const float*)d_in[3];
    const float* bigr_v = (const float*)d_in[4];
    float* out = (float*)d_out;                       // BH*SQ*DH
    float* P   = out + (size_t)BH * SQ * DH;          // BH*SQ*SK
    float* partial = (float*)d_ws;                    // [4][SQ][BH] fp32 = 1 MB

    k_scores<<<dim3(16, 16, BH), 256, 0, stream>>>(query, key, P);
    k_rel_exp<<<dim3(4, 128), 256, 0, stream>>>(query, bigr_k, P, partial);
    k_pv<<<dim3(16, BH), 256, 0, stream>>>(P, value, partial, out);
    k_pr<<<dim3(SQ), 256, 0, stream>>>(P, bigr_v, out);
}